// Round 5
// baseline (1525.045 us; speedup 1.0000x reference)
//
#include <hip/hip_runtime.h>
#include <hip/hip_bf16.h>
#include <stdint.h>

#define N_NODES 100000
#define N_EDGES 1600000
#define N_GRAPHS 512
#define IN_F 50
#define HID 128

typedef __attribute__((ext_vector_type(8))) short bf16x8;
typedef __attribute__((ext_vector_type(4))) float f32x4;

__device__ __forceinline__ float bf2f(unsigned short s) {
    return __uint_as_float(((unsigned)s) << 16);
}
__device__ __forceinline__ unsigned short f2bf(float f) {
    unsigned u = __float_as_uint(f);
    u = (u + 0x7FFFu + ((u >> 16) & 1u)) >> 16;   // round-to-nearest-even
    return (unsigned short)u;
}

// counts[g] = #nodes in graph g (batch is sorted) -- atomic-free binary search
__global__ void count_nodes(const int* __restrict__ batch, float* __restrict__ counts) {
    int g = blockIdx.x * blockDim.x + threadIdx.x;
    if (g >= N_GRAPHS) return;
    int lo = 0, hi = N_NODES;
    while (lo < hi) { int m = (lo + hi) >> 1; if (batch[m] < g) lo = m + 1; else hi = m; }
    int lo2 = lo, hi2 = N_NODES;
    while (lo2 < hi2) { int m = (lo2 + hi2) >> 1; if (batch[m] < g + 1) lo2 = m + 1; else hi2 = m; }
    counts[g] = (float)(lo2 - lo);
}

// ---------------- CSR build ----------------
__global__ void deg_hist(const int* __restrict__ dst, int* __restrict__ deg) {
    int gid = blockIdx.x * blockDim.x + threadIdx.x;
    int stride = gridDim.x * blockDim.x;
    for (int e = gid; e < N_EDGES; e += stride) atomicAdd(&deg[dst[e]], 1);
}

// -------- 3-phase grid-wide exclusive scan of deg[100000] --------
#define SCAN_BLOCKS ((N_NODES + 1023) / 1024)   // 98

__global__ __launch_bounds__(256) void scan_phase1(const int* __restrict__ deg,
                                                   int* __restrict__ blocksum) {
    __shared__ int red[256];
    int b = blockIdx.x, t = threadIdx.x;
    int base = b * 1024 + t * 4;
    int s = 0;
#pragma unroll
    for (int i = 0; i < 4; i++) { int idx = base + i; if (idx < N_NODES) s += deg[idx]; }
    red[t] = s;
    __syncthreads();
    for (int off = 128; off > 0; off >>= 1) {
        if (t < off) red[t] += red[t + off];
        __syncthreads();
    }
    if (t == 0) blocksum[b] = red[0];
}

__global__ __launch_bounds__(128) void scan_phase2(const int* __restrict__ blocksum,
                                                   int* __restrict__ blockoff) {
    __shared__ int v[SCAN_BLOCKS];
    int t = threadIdx.x;
    if (t < SCAN_BLOCKS) v[t] = blocksum[t];
    __syncthreads();
    if (t == 0) {
        int run = 0;
        for (int i = 0; i < SCAN_BLOCKS; i++) { blockoff[i] = run; run += v[i]; }
        blockoff[SCAN_BLOCKS] = run;
    }
}

__global__ __launch_bounds__(256) void scan_phase3(const int* __restrict__ deg,
                                                   const int* __restrict__ blockoff,
                                                   int* __restrict__ rowptr,
                                                   int* __restrict__ cursor) {
    __shared__ int red[256];
    int b = blockIdx.x, t = threadIdx.x;
    int base = b * 1024 + t * 4;
    int e[4];
    int s = 0;
#pragma unroll
    for (int i = 0; i < 4; i++) {
        int idx = base + i;
        e[i] = (idx < N_NODES) ? deg[idx] : 0;
        s += e[i];
    }
    red[t] = s;
    __syncthreads();
    for (int off = 1; off < 256; off <<= 1) {
        int u = (t >= off) ? red[t - off] : 0;
        __syncthreads();
        red[t] += u;
        __syncthreads();
    }
    int prefix = red[t] - s + blockoff[b];   // exclusive prefix of this thread's 4 elems
#pragma unroll
    for (int i = 0; i < 4; i++) {
        int idx = base + i;
        if (idx < N_NODES) { rowptr[idx] = prefix; cursor[idx] = prefix; prefix += e[i]; }
    }
    if (b == 0 && t == 0) rowptr[N_NODES] = blockoff[SCAN_BLOCKS];
}

__global__ void csr_fill(const int* __restrict__ src, const int* __restrict__ dst,
                         int* __restrict__ cursor, int* __restrict__ csr_src) {
    int gid = blockIdx.x * blockDim.x + threadIdx.x;
    int stride = gridDim.x * blockDim.x;
    for (int e = gid; e < N_EDGES; e += stride) {
        int d = dst[e];
        int p = atomicAdd(&cursor[d], 1);
        csr_src[p] = src[e];
    }
}

// ---------------- dtype prep ----------------
// all six weight matrices f32 -> bf16 in one launch (layer1 pair zero-padded 50->64)
__global__ __launch_bounds__(256) void wconv_all(
    const float* __restrict__ Wr1, const float* __restrict__ Wo1,
    const float* __restrict__ Wr2, const float* __restrict__ Wo2,
    const float* __restrict__ Wr3, const float* __restrict__ Wo3,
    unsigned short* __restrict__ o_r1, unsigned short* __restrict__ o_o1,
    unsigned short* __restrict__ o_r2, unsigned short* __restrict__ o_o2,
    unsigned short* __restrict__ o_r3, unsigned short* __restrict__ o_o3) {
    int idx = blockIdx.x * 256 + threadIdx.x;
    if (idx < 128 * 64) {
        int n = idx >> 6, k = idx & 63;
        unsigned short a = 0, b = 0;
        if (k < IN_F) { a = f2bf(Wr1[n * IN_F + k]); b = f2bf(Wo1[n * IN_F + k]); }
        o_r1[idx] = a; o_o1[idx] = b;
        return;
    }
    idx -= 128 * 64;
    if (idx < 128 * 128) {
        o_r2[idx] = f2bf(Wr2[idx]); o_o2[idx] = f2bf(Wo2[idx]);
        o_r3[idx] = f2bf(Wr3[idx]); o_o3[idx] = f2bf(Wo3[idx]);
    }
}

// x[100k][50] f32 -> xbf[100k][64] bf16 zero-padded
__global__ void xconv(const float* __restrict__ x, unsigned short* __restrict__ xbf) {
    int idx = blockIdx.x * 256 + threadIdx.x;
    if (idx >= N_NODES * 64) return;
    int n = idx >> 6, c = idx & 63;
    float v = (c < IN_F) ? x[(size_t)n * IN_F + c] : 0.f;
    xbf[idx] = f2bf(v);
}

// ---------------- pull aggregation (writes bf16) ----------------
// wave per node, F=50 f32 in -> bf16 [64] out (padded)
__global__ __launch_bounds__(256) void gather_f50(const float* __restrict__ x,
                                                  const int* __restrict__ rowptr,
                                                  const int* __restrict__ csr_src,
                                                  unsigned short* __restrict__ aggbf) {
    int gid = blockIdx.x * blockDim.x + threadIdx.x;
    int n = gid >> 6;
    int lane = threadIdx.x & 63;
    if (n >= N_NODES) return;
    int jb = rowptr[n], je = rowptr[n + 1];
    float acc = 0.f;
    int j = jb;
    for (; j + 1 < je; j += 2) {
        int s0 = csr_src[j], s1 = csr_src[j + 1];
        float v0 = 0.f, v1 = 0.f;
        if (lane < IN_F) { v0 = x[(size_t)s0 * IN_F + lane]; v1 = x[(size_t)s1 * IN_F + lane]; }
        acc += v0 + v1;
    }
    if (j < je) {
        int s0 = csr_src[j];
        if (lane < IN_F) acc += x[(size_t)s0 * IN_F + lane];
    }
    aggbf[(size_t)n * 64 + lane] = (lane < IN_F) ? f2bf(acc) : (unsigned short)0;
}

// wave per node, F=128 bf16 source: lane holds 2 features (one dword), bf16 out
__global__ __launch_bounds__(256) void gather_bf128(const unsigned short* __restrict__ h,
                                                    const int* __restrict__ rowptr,
                                                    const int* __restrict__ csr_src,
                                                    unsigned short* __restrict__ aggbf) {
    int gid = blockIdx.x * blockDim.x + threadIdx.x;
    int n = gid >> 6;
    int lane = threadIdx.x & 63;
    if (n >= N_NODES) return;
    int jb = rowptr[n], je = rowptr[n + 1];
    float acc0 = 0.f, acc1 = 0.f;
    const unsigned* hu = reinterpret_cast<const unsigned*>(h);
    int j = jb;
    for (; j + 1 < je; j += 2) {
        int s0 = csr_src[j], s1 = csr_src[j + 1];
        unsigned v0 = hu[(size_t)s0 * 64 + lane];
        unsigned v1 = hu[(size_t)s1 * 64 + lane];
        acc0 += bf2f((unsigned short)(v0 & 0xFFFF)) + bf2f((unsigned short)(v1 & 0xFFFF));
        acc1 += bf2f((unsigned short)(v0 >> 16)) + bf2f((unsigned short)(v1 >> 16));
    }
    if (j < je) {
        int s0 = csr_src[j];
        unsigned v0 = hu[(size_t)s0 * 64 + lane];
        acc0 += bf2f((unsigned short)(v0 & 0xFFFF));
        acc1 += bf2f((unsigned short)(v0 >> 16));
    }
    unsigned pk = (unsigned)f2bf(acc0) | ((unsigned)f2bf(acc1) << 16);
    reinterpret_cast<unsigned*>(aggbf)[(size_t)n * 64 + lane] = pk;
}

// ---------------- MFMA fused linear, v2: LDS-staged weights ----------------
// out = [relu](A1 @ B1^T + bias + A2 @ B2^T). A bf16 [M][K], B bf16 [128][K] (W layout).
// Block = 256 thr = 4 waves x 32 rows (BM=128). Weights staged in 32KB LDS with XOR
// swizzle (slot*16 ^ ((n&7)<<4)) -> fragment reads spread across all 32 banks.
// MFMA operands SWAPPED: D = W_frag * A_frag -> D[n][node]; lane&15 = node,
// row (kh*4+r) = 4 CONSECUTIVE output cols -> uint2 contiguous stores (no write amp).
// In-place safe (hout may alias A2): each wave reads only its own rows before writing.
template <int K1, int K2, bool RELU, bool POOL>
__global__ __launch_bounds__(256) void mfma_linear(
    const unsigned short* __restrict__ A1, const unsigned short* __restrict__ A2,
    const unsigned short* __restrict__ B1, const unsigned short* __restrict__ B2,
    const float* __restrict__ bias, unsigned short* __restrict__ hout,
    const int* __restrict__ batch, float* __restrict__ pooled) {
    __shared__ unsigned char ldsb[32768];
    const int tid = threadIdx.x;
    const int wave = tid >> 6;
    const int lane = tid & 63;
    const int ar = lane & 15;          // node index within 16-tile (MFMA "B" col / D col)
    const int kh = lane >> 4;          // k-chunk (8 elems) / D row-quad
    const int m0 = blockIdx.x * 128 + wave * 32;
    const int swz = (ar & 7) << 4;

    f32x4 acc[2][8];
#pragma unroll
    for (int mt = 0; mt < 2; mt++)
#pragma unroll
        for (int nt = 0; nt < 8; nt++) acc[mt][nt] = (f32x4){0.f, 0.f, 0.f, 0.f};

    auto stage = [&](const unsigned short* B, int K) {
        const int cpr = K >> 3;                  // 16B chunks per row
        const int rowBytes = K * 2;
        const int total = 128 * cpr;
        for (int ci = tid; ci < total; ci += 256) {
            int n = ci / cpr, slot = ci - n * cpr;
            uint4 v = *reinterpret_cast<const uint4*>(B + n * K + slot * 8);
            int byteoff = n * rowBytes + ((slot * 16) ^ ((n & 7) << 4));
            *reinterpret_cast<uint4*>(&ldsb[byteoff]) = v;
        }
    };

    auto kloop = [&](const unsigned short* A, int K) {
        const int rowBytes = K * 2;
        int r0 = m0 + ar;       if (r0 > N_NODES - 1) r0 = N_NODES - 1;
        int r1 = m0 + 16 + ar;  if (r1 > N_NODES - 1) r1 = N_NODES - 1;
        const unsigned short* a0p = A + (size_t)r0 * K;
        const unsigned short* a1p = A + (size_t)r1 * K;
#pragma unroll
        for (int ks = 0; ks < K / 32; ks++) {
            bf16x8 a0 = *reinterpret_cast<const bf16x8*>(a0p + ks * 32 + kh * 8);
            bf16x8 a1 = *reinterpret_cast<const bf16x8*>(a1p + ks * 32 + kh * 8);
#pragma unroll
            for (int nt = 0; nt < 8; nt++) {
                int n = nt * 16 + ar;
                int byteoff = n * rowBytes + ((ks * 64 + kh * 16) ^ swz);
                bf16x8 b = *reinterpret_cast<const bf16x8*>(&ldsb[byteoff]);
                acc[0][nt] = __builtin_amdgcn_mfma_f32_16x16x32_bf16(b, a0, acc[0][nt], 0, 0, 0);
                acc[1][nt] = __builtin_amdgcn_mfma_f32_16x16x32_bf16(b, a1, acc[1][nt], 0, 0, 0);
            }
        }
    };

    stage(B1, K1);
    __syncthreads();
    kloop(A1, K1);
    __syncthreads();
    stage(B2, K2);
    __syncthreads();
    kloop(A2, K2);

    // epilogue: lane holds, for node (ar) and each nt, 4 consecutive out-cols kh*4+r
    float4 bv[8];
#pragma unroll
    for (int nt = 0; nt < 8; nt++)
        bv[nt] = *reinterpret_cast<const float4*>(bias + nt * 16 + kh * 4);

#pragma unroll
    for (int mt = 0; mt < 2; mt++) {
        int node = m0 + mt * 16 + ar;
        if (node >= N_NODES) continue;
        if (RELU) {
#pragma unroll
            for (int nt = 0; nt < 8; nt++) {
                float v0 = fmaxf(acc[mt][nt][0] + bv[nt].x, 0.f);
                float v1 = fmaxf(acc[mt][nt][1] + bv[nt].y, 0.f);
                float v2 = fmaxf(acc[mt][nt][2] + bv[nt].z, 0.f);
                float v3 = fmaxf(acc[mt][nt][3] + bv[nt].w, 0.f);
                uint2 pk;
                pk.x = (unsigned)f2bf(v0) | ((unsigned)f2bf(v1) << 16);
                pk.y = (unsigned)f2bf(v2) | ((unsigned)f2bf(v3) << 16);
                *reinterpret_cast<uint2*>(hout + (size_t)node * HID + nt * 16 + kh * 4) = pk;
            }
        }
        if (POOL) {
            int g = batch[node];
            float* pg = pooled + (size_t)g * HID + kh * 4;
#pragma unroll
            for (int nt = 0; nt < 8; nt++) {
                atomicAdd(pg + nt * 16 + 0, acc[mt][nt][0] + bv[nt].x);
                atomicAdd(pg + nt * 16 + 1, acc[mt][nt][1] + bv[nt].y);
                atomicAdd(pg + nt * 16 + 2, acc[mt][nt][2] + bv[nt].z);
                atomicAdd(pg + nt * 16 + 3, acc[mt][nt][3] + bv[nt].w);
            }
        }
    }
}

__global__ void final_linear(const float* __restrict__ pooled, const float* __restrict__ counts,
                             const float* __restrict__ W_lin, const float* __restrict__ b_lin,
                             float* __restrict__ out) {
    __shared__ float p[HID];
    int g = blockIdx.x, tid = threadIdx.x;
    float c = fmaxf(counts[g], 1.f);
    p[tid] = pooled[(size_t)g * HID + tid] / c;
    __syncthreads();
    if (tid < 4) {
        float s = b_lin[tid];
#pragma unroll 8
        for (int k = 0; k < HID; k++) s += p[k] * W_lin[tid * HID + k];
        out[g * 4 + tid] = s;
    }
}

extern "C" void kernel_launch(void* const* d_in, const int* in_sizes, int n_in,
                              void* d_out, int out_size, void* d_ws, size_t ws_size,
                              hipStream_t stream) {
    (void)in_sizes; (void)n_in; (void)out_size; (void)ws_size;
    const float* x      = (const float*)d_in[0];
    const int*   ei     = (const int*)d_in[1];
    const int*   batch  = (const int*)d_in[2];
    const float* W_rel1 = (const float*)d_in[3];
    const float* b_rel1 = (const float*)d_in[4];
    const float* W_root1= (const float*)d_in[5];
    const float* W_rel2 = (const float*)d_in[6];
    const float* b_rel2 = (const float*)d_in[7];
    const float* W_root2= (const float*)d_in[8];
    const float* W_rel3 = (const float*)d_in[9];
    const float* b_rel3 = (const float*)d_in[10];
    const float* W_root3= (const float*)d_in[11];
    const float* W_lin  = (const float*)d_in[12];
    const float* b_lin  = (const float*)d_in[13];
    const int* src = ei;
    const int* dst = ei + N_EDGES;

    char* ws = (char*)d_ws;
    size_t off = 0;
    auto alloc = [&](size_t bytes) { void* p = ws + off; off += (bytes + 255) & ~(size_t)255; return p; };
    unsigned short* aggbf    = (unsigned short*)alloc((size_t)N_NODES * HID * 2); // 25.6 MB (layer1 uses [.][64] slice)
    unsigned short* h1       = (unsigned short*)alloc((size_t)N_NODES * HID * 2); // 25.6 MB (layers 2,3 in-place)
    unsigned short* xbf      = (unsigned short*)alloc((size_t)N_NODES * 64 * 2);  // 12.8 MB
    int*            deg      = (int*)alloc((size_t)N_NODES * 4);
    int*            rowptr   = (int*)alloc((size_t)(N_NODES + 1) * 4);
    int*            cursor   = (int*)alloc((size_t)N_NODES * 4);
    int*            csr_src  = (int*)alloc((size_t)N_EDGES * 4);                  // 6.4 MB
    int*            blocksum = (int*)alloc((size_t)(SCAN_BLOCKS + 1) * 4);
    int*            blockoff = (int*)alloc((size_t)(SCAN_BLOCKS + 1) * 4);
    unsigned short* Wb_rel1  = (unsigned short*)alloc(128 * 64 * 2);
    unsigned short* Wb_root1 = (unsigned short*)alloc(128 * 64 * 2);
    unsigned short* Wb_rel2  = (unsigned short*)alloc(128 * 128 * 2);
    unsigned short* Wb_root2 = (unsigned short*)alloc(128 * 128 * 2);
    unsigned short* Wb_rel3  = (unsigned short*)alloc(128 * 128 * 2);
    unsigned short* Wb_root3 = (unsigned short*)alloc(128 * 128 * 2);
    float*          pooled   = (float*)alloc((size_t)N_GRAPHS * HID * 4);
    float*          counts   = (float*)alloc(N_GRAPHS * 4);

    // ---- CSR build (parallel scan)
    hipMemsetAsync(deg, 0, (size_t)N_NODES * 4, stream);
    deg_hist<<<2048, 256, 0, stream>>>(dst, deg);
    scan_phase1<<<SCAN_BLOCKS, 256, 0, stream>>>(deg, blocksum);
    scan_phase2<<<1, 128, 0, stream>>>(blocksum, blockoff);
    scan_phase3<<<SCAN_BLOCKS, 256, 0, stream>>>(deg, blockoff, rowptr, cursor);
    csr_fill<<<2048, 256, 0, stream>>>(src, dst, cursor, csr_src);

    // ---- dtype prep
    wconv_all<<<(128 * 64 + 128 * 128 + 255) / 256, 256, 0, stream>>>(
        W_rel1, W_root1, W_rel2, W_root2, W_rel3, W_root3,
        Wb_rel1, Wb_root1, Wb_rel2, Wb_root2, Wb_rel3, Wb_root3);
    xconv<<<(N_NODES * 64 + 255) / 256, 256, 0, stream>>>(x, xbf);
    hipMemsetAsync(pooled, 0, (size_t)N_GRAPHS * HID * 4, stream);
    count_nodes<<<2, 256, 0, stream>>>(batch, counts);

    const int GATHER_BLOCKS = (N_NODES * 64 + 255) / 256;  // wave per node
    const int MFMA_BLOCKS = (N_NODES + 127) / 128;         // BM=128

    // ---- layer 1: pull-aggregate x (F=50), MFMA linears + relu -> h1 (bf16)
    gather_f50<<<GATHER_BLOCKS, 256, 0, stream>>>(x, rowptr, csr_src, aggbf);
    mfma_linear<64, 64, true, false><<<MFMA_BLOCKS, 256, 0, stream>>>(
        aggbf, xbf, Wb_rel1, Wb_root1, b_rel1, h1, nullptr, nullptr);

    // ---- layer 2: pull-aggregate h1 (F=128 bf16), MFMA linears + relu -> h1 (in-place)
    gather_bf128<<<GATHER_BLOCKS, 256, 0, stream>>>(h1, rowptr, csr_src, aggbf);
    mfma_linear<128, 128, true, false><<<MFMA_BLOCKS, 256, 0, stream>>>(
        aggbf, h1, Wb_rel2, Wb_root2, b_rel2, h1, nullptr, nullptr);

    // ---- layer 3: pull-aggregate h1, MFMA linears (no relu) + fused mean-pool
    gather_bf128<<<GATHER_BLOCKS, 256, 0, stream>>>(h1, rowptr, csr_src, aggbf);
    mfma_linear<128, 128, false, true><<<MFMA_BLOCKS, 256, 0, stream>>>(
        aggbf, h1, Wb_rel3, Wb_root3, b_rel3, nullptr, batch, pooled);

    final_linear<<<N_GRAPHS, HID, 0, stream>>>(pooled, counts, W_lin, b_lin, (float*)d_out);
}